// Round 1
// baseline (1090.664 us; speedup 1.0000x reference)
//
#include <hip/hip_runtime.h>
#include <math.h>

#define LEAKY 0.2f

// ---------------- CSR build ----------------

__global__ void init_kernel(int* cnt, int* fillpos, int N) {
    int i = blockIdx.x * blockDim.x + threadIdx.x;
    if (i < N) { cnt[i] = 1; fillpos[i] = 0; }  // 1 = self-loop
}

__global__ void count_kernel(const int* __restrict__ dst, int* cnt, int E) {
    int e = blockIdx.x * blockDim.x + threadIdx.x;
    if (e < E) atomicAdd(&cnt[dst[e]], 1);
}

__global__ void dis_kernel(const int* __restrict__ cnt, float* dis, int N) {
    int i = blockIdx.x * blockDim.x + threadIdx.x;
    if (i < N) dis[i] = 1.0f / sqrtf((float)cnt[i]);
}

// 3-kernel exclusive scan of cnt -> rowptr (N+1 entries)
__global__ void scan_block(const int* __restrict__ cnt, int* rowptr, int* bsum, int n) {
    __shared__ int s[256];
    int t = threadIdx.x;
    int i = blockIdx.x * 256 + t;
    int v = (i < n) ? cnt[i] : 0;
    s[t] = v; __syncthreads();
    for (int off = 1; off < 256; off <<= 1) {
        int a = (t >= off) ? s[t - off] : 0;
        __syncthreads();
        s[t] += a;
        __syncthreads();
    }
    if (i < n) rowptr[i] = s[t] - v;
    if (t == 255) bsum[blockIdx.x] = s[255];
}

__global__ void scan_tops(int* bsum, int nb, int* rowptr, int n) {
    __shared__ int s[512];
    int t = threadIdx.x;
    int v = (t < nb) ? bsum[t] : 0;
    s[t] = v; __syncthreads();
    for (int off = 1; off < 512; off <<= 1) {
        int a = (t >= off) ? s[t - off] : 0;
        __syncthreads();
        s[t] += a;
        __syncthreads();
    }
    if (t < nb) bsum[t] = s[t] - v;
    if (t == 511) rowptr[n] = s[511];
}

__global__ void scan_add(int* rowptr, const int* __restrict__ bsum, int n) {
    int i = blockIdx.x * 256 + threadIdx.x;
    if (i < n) rowptr[i] += bsum[blockIdx.x];
}

__global__ void fill_kernel(const int* __restrict__ src, const int* __restrict__ dst,
                            const int* __restrict__ rowptr, int* fillpos, int* col,
                            int E, int N) {
    int e = blockIdx.x * blockDim.x + threadIdx.x;
    if (e >= E + N) return;
    int s, d;
    if (e < E) { s = src[e]; d = dst[e]; }
    else       { s = e - E;  d = s; }      // self-loop
    int pos = atomicAdd(&fillpos[d], 1);
    col[rowptr[d] + pos] = s;
}

// ---------------- GEMM1: [M,256] @ [256,128] ----------------
// 64x64 tile, 256 threads, 4x4 micro-tile, BK=16
__global__ __launch_bounds__(256) void gemm_256_128(
        const float* __restrict__ A, const float* __restrict__ B,
        float* __restrict__ C, int M) {
    __shared__ float As[16][65];
    __shared__ float Bs[16][64];
    int t = threadIdx.x;
    int bm0 = blockIdx.x * 64;
    int bn0 = blockIdx.y * 64;
    int tm0 = (t / 16) * 4;
    int tn0 = (t % 16) * 4;
    int lm  = t / 4;            // A-load row (0..63)
    int lk0 = (t % 4) * 4;      // A-load k base
    int lbk  = t / 16;          // B-load k (0..15)
    int lbn0 = (t % 16) * 4;    // B-load n base
    int arow = bm0 + lm;
    bool aval = arow < M;
    float acc[4][4] = {};
    for (int kb = 0; kb < 256; kb += 16) {
        #pragma unroll
        for (int i = 0; i < 4; ++i) {
            int k = lk0 + i;
            As[k][lm] = aval ? A[(size_t)arow * 256 + kb + k] : 0.0f;
        }
        #pragma unroll
        for (int j = 0; j < 4; ++j)
            Bs[lbk][lbn0 + j] = B[(size_t)(kb + lbk) * 128 + bn0 + lbn0 + j];
        __syncthreads();
        #pragma unroll
        for (int kk = 0; kk < 16; ++kk) {
            float a[4], b[4];
            #pragma unroll
            for (int i = 0; i < 4; ++i) a[i] = As[kk][tm0 + i];
            #pragma unroll
            for (int j = 0; j < 4; ++j) b[j] = Bs[kk][tn0 + j];
            #pragma unroll
            for (int i = 0; i < 4; ++i)
                #pragma unroll
                for (int j = 0; j < 4; ++j)
                    acc[i][j] += a[i] * b[j];
        }
        __syncthreads();
    }
    #pragma unroll
    for (int i = 0; i < 4; ++i) {
        int r = bm0 + tm0 + i;
        if (r < M) {
            #pragma unroll
            for (int j = 0; j < 4; ++j)
                C[(size_t)r * 128 + bn0 + tn0 + j] = acc[i][j];
        }
    }
}

// ---------------- prop, width 128: one wave per node ----------------
__global__ __launch_bounds__(256) void prop128(
        const float* __restrict__ h, const int* __restrict__ rowptr,
        const int* __restrict__ col, const float* __restrict__ dis,
        const float* __restrict__ bias, float* __restrict__ out, int N) {
    int n = (blockIdx.x * 256 + threadIdx.x) >> 6;
    int lane = threadIdx.x & 63;
    if (n >= N) return;
    int beg = rowptr[n], end = rowptr[n + 1];
    float acc0 = 0.f, acc1 = 0.f;
    for (int j = beg; j < end; ++j) {
        int s = col[j];
        float w = dis[s];
        const float* hr = h + (size_t)s * 128;
        acc0 += w * hr[lane];
        acc1 += w * hr[lane + 64];
    }
    float dn = dis[n];
    float o0 = dn * acc0 + bias[lane];
    float o1 = dn * acc1 + bias[lane + 64];
    o0 = o0 > 0.f ? o0 : LEAKY * o0;
    o1 = o1 > 0.f ? o1 : LEAKY * o1;
    out[(size_t)n * 128 + lane]      = o0;
    out[(size_t)n * 128 + lane + 64] = o1;
}

// ---------------- GEMM2: [M,128] @ [128,16] ----------------
// block handles 64 nodes; x tile + W in LDS
__global__ __launch_bounds__(256) void gemm_128_16(
        const float* __restrict__ A, const float* __restrict__ W,
        float* __restrict__ C, int M) {
    __shared__ float sx[64 * 129];
    __shared__ float sw[128 * 16];
    int t = threadIdx.x;
    int n0 = blockIdx.x * 64;
    for (int i = t; i < 2048; i += 256) sw[i] = W[i];
    #pragma unroll
    for (int i = 0; i < 32; ++i) {
        int l = t + i * 256;
        int node = l >> 7, k = l & 127;
        int gn = n0 + node;
        sx[node * 129 + k] = (gn < M) ? A[(size_t)gn * 128 + k] : 0.f;
    }
    __syncthreads();
    int n = t >> 2;            // 0..63
    int c0 = (t & 3) * 4;      // 0,4,8,12
    const float4* sw4 = (const float4*)sw;
    float4 acc = make_float4(0.f, 0.f, 0.f, 0.f);
    for (int k = 0; k < 128; ++k) {
        float xv = sx[n * 129 + k];
        float4 wv = sw4[k * 4 + (t & 3)];
        acc.x += xv * wv.x; acc.y += xv * wv.y;
        acc.z += xv * wv.z; acc.w += xv * wv.w;
    }
    int gn = n0 + n;
    if (gn < M) {
        float* dst = C + (size_t)gn * 16 + c0;
        dst[0] = acc.x; dst[1] = acc.y; dst[2] = acc.z; dst[3] = acc.w;
    }
}

// ---------------- prop, width 16: 16 lanes per node ----------------
__global__ __launch_bounds__(256) void prop16(
        const float* __restrict__ h, const int* __restrict__ rowptr,
        const int* __restrict__ col, const float* __restrict__ dis,
        const float* __restrict__ bias, float* __restrict__ out,
        int N, int act) {
    int t = blockIdx.x * 256 + threadIdx.x;
    int n = t >> 4, f = t & 15;
    if (n >= N) return;
    int beg = rowptr[n], end = rowptr[n + 1];
    float acc = 0.f;
    for (int j = beg; j < end; ++j) {
        int s = col[j];
        acc += dis[s] * h[(size_t)s * 16 + f];
    }
    float o = dis[n] * acc;
    if (act) {
        o += bias[f];
        o = o > 0.f ? o : LEAKY * o;
    }
    out[(size_t)n * 16 + f] = o;
}

// ---------------- GEMM3: [M,16] @ [16,40] + b ----------------
__global__ __launch_bounds__(256) void gemm_16_40(
        const float* __restrict__ P, const float* __restrict__ W,
        const float* __restrict__ b, float* __restrict__ out, int total) {
    __shared__ float sw[16 * 40];
    __shared__ float sb[40];
    int t = threadIdx.x;
    for (int i = t; i < 640; i += 256) sw[i] = W[i];
    if (t < 40) sb[t] = b[t];
    __syncthreads();
    int idx = blockIdx.x * 256 + t;
    if (idx >= total) return;
    int n = idx / 40, c = idx % 40;
    float acc = sb[c];
    const float* pr = P + (size_t)n * 16;
    #pragma unroll
    for (int k = 0; k < 16; ++k) acc += pr[k] * sw[k * 40 + c];
    out[idx] = acc;
}

// ---------------- launch ----------------

extern "C" void kernel_launch(void* const* d_in, const int* in_sizes, int n_in,
                              void* d_out, int out_size, void* d_ws, size_t ws_size,
                              hipStream_t stream) {
    const float* x  = (const float*)d_in[0];
    const int*   ei = (const int*)d_in[1];
    const float* W1 = (const float*)d_in[2];
    const float* b1 = (const float*)d_in[3];
    const float* W2 = (const float*)d_in[4];
    const float* b2 = (const float*)d_in[5];
    const float* W3 = (const float*)d_in[6];
    const float* b3 = (const float*)d_in[7];
    float* out = (float*)d_out;

    int N = in_sizes[0] / 256;   // 100000
    int E = in_sizes[1] / 2;     // 3200000
    const int* src = ei;
    const int* dst = ei + E;

    char* w = (char*)d_ws;
    auto alloc = [&](size_t bytes) {
        char* p = w;
        w += (bytes + 255) & ~(size_t)255;
        return p;
    };
    int NB = (N + 255) / 256;
    int*   cnt     = (int*)  alloc((size_t)N * 4);
    int*   rowptr  = (int*)  alloc((size_t)(N + 1) * 4);
    int*   fillpos = (int*)  alloc((size_t)N * 4);
    int*   bsum    = (int*)  alloc((size_t)NB * 4);
    int*   colx    = (int*)  alloc((size_t)(E + N) * 4);
    float* dis     = (float*)alloc((size_t)N * 4);
    float* bufA    = (float*)alloc((size_t)N * 128 * 4);
    float* bufB    = (float*)alloc((size_t)N * 128 * 4);

    float* h1 = bufA;                       // [N,128]
    float* x1 = bufB;                       // [N,128]
    float* h2 = bufA;                       // [N,16]  (h1 dead)
    float* x2 = bufA + (size_t)N * 16;      // [N,16]
    float* p3 = bufA + (size_t)N * 32;      // [N,16]

    int gN = (N + 255) / 256;
    init_kernel <<<gN, 256, 0, stream>>>(cnt, fillpos, N);
    count_kernel<<<(E + 255) / 256, 256, 0, stream>>>(dst, cnt, E);
    dis_kernel  <<<gN, 256, 0, stream>>>(cnt, dis, N);
    scan_block  <<<NB, 256, 0, stream>>>(cnt, rowptr, bsum, N);
    scan_tops   <<<1, 512, 0, stream>>>(bsum, NB, rowptr, N);
    scan_add    <<<NB, 256, 0, stream>>>(rowptr, bsum, N);
    fill_kernel <<<(E + N + 255) / 256, 256, 0, stream>>>(src, dst, rowptr,
                                                          fillpos, colx, E, N);

    gemm_256_128<<<dim3((N + 63) / 64, 2), 256, 0, stream>>>(x, W1, h1, N);
    prop128     <<<(N * 64 + 255) / 256, 256, 0, stream>>>(h1, rowptr, colx,
                                                           dis, b1, x1, N);
    gemm_128_16 <<<(N + 63) / 64, 256, 0, stream>>>(x1, W2, h2, N);
    prop16      <<<(N * 16 + 255) / 256, 256, 0, stream>>>(h2, rowptr, colx,
                                                           dis, b2, x2, N, 1);
    prop16      <<<(N * 16 + 255) / 256, 256, 0, stream>>>(x2, rowptr, colx,
                                                           dis, nullptr, p3, N, 0);
    gemm_16_40  <<<(N * 40 + 255) / 256, 256, 0, stream>>>(p3, W3, b3, out,
                                                           N * 40);
}

// Round 2
// 880.767 us; speedup vs baseline: 1.2383x; 1.2383x over previous
//
#include <hip/hip_runtime.h>
#include <math.h>

#define LEAKY 0.2f

// ---------------- CSR build ----------------

__global__ void init_kernel(int* cnt, int* fillpos, int N) {
    int i = blockIdx.x * blockDim.x + threadIdx.x;
    if (i < N) { cnt[i] = 1; fillpos[i] = 0; }  // 1 = self-loop
}

__global__ void count_kernel(const int* __restrict__ dst, int* cnt, int E) {
    int e = blockIdx.x * blockDim.x + threadIdx.x;
    if (e < E) atomicAdd(&cnt[dst[e]], 1);
}

__global__ void dis_kernel(const int* __restrict__ cnt, float* dis, int N) {
    int i = blockIdx.x * blockDim.x + threadIdx.x;
    if (i < N) dis[i] = 1.0f / sqrtf((float)cnt[i]);
}

__global__ void scan_block(const int* __restrict__ cnt, int* rowptr, int* bsum, int n) {
    __shared__ int s[256];
    int t = threadIdx.x;
    int i = blockIdx.x * 256 + t;
    int v = (i < n) ? cnt[i] : 0;
    s[t] = v; __syncthreads();
    for (int off = 1; off < 256; off <<= 1) {
        int a = (t >= off) ? s[t - off] : 0;
        __syncthreads();
        s[t] += a;
        __syncthreads();
    }
    if (i < n) rowptr[i] = s[t] - v;
    if (t == 255) bsum[blockIdx.x] = s[255];
}

__global__ void scan_tops(int* bsum, int nb, int* rowptr, int n) {
    __shared__ int s[512];
    int t = threadIdx.x;
    int v = (t < nb) ? bsum[t] : 0;
    s[t] = v; __syncthreads();
    for (int off = 1; off < 512; off <<= 1) {
        int a = (t >= off) ? s[t - off] : 0;
        __syncthreads();
        s[t] += a;
        __syncthreads();
    }
    if (t < nb) bsum[t] = s[t] - v;
    if (t == 511) rowptr[n] = s[511];
}

__global__ void scan_add(int* rowptr, const int* __restrict__ bsum, int n) {
    int i = blockIdx.x * 256 + threadIdx.x;
    if (i < n) rowptr[i] += bsum[blockIdx.x];
}

__global__ void fill_kernel(const int* __restrict__ src, const int* __restrict__ dst,
                            const int* __restrict__ rowptr, int* fillpos, int* col,
                            int E, int N) {
    int e = blockIdx.x * blockDim.x + threadIdx.x;
    if (e >= E + N) return;
    int s, d;
    if (e < E) { s = src[e]; d = dst[e]; }
    else       { s = e - E;  d = s; }      // self-loop
    int pos = atomicAdd(&fillpos[d], 1);
    col[rowptr[d] + pos] = s;
}

// ---------------- GEMM1: [M,256] @ [256,128], epilogue *= dis[row] ----------------
// 64x128 tile, 256 threads, 8x4 micro-tile, BK=16, float4 LDS reads
__global__ __launch_bounds__(256) void gemm_256_128(
        const float* __restrict__ A, const float* __restrict__ B,
        const float* __restrict__ dis, float* __restrict__ C, int M) {
    __shared__ __align__(16) float As[16][68];
    __shared__ __align__(16) float Bs[16][128];
    int t = threadIdx.x;
    int bm0 = blockIdx.x * 64;
    int lm  = t >> 2;            // A-load row 0..63
    int lk0 = (t & 3) * 4;       // A-load k base
    int lbk  = t >> 4;           // B-load k 0..15
    int lbn0 = (t & 15) * 8;     // B-load n base
    int arow = bm0 + lm;
    bool aval = arow < M;
    const float* Arow = A + (size_t)arow * 256;
    int tm0 = (t >> 5) * 8;      // micro row base
    int tn0 = (t & 31) * 4;      // micro col base
    float acc[8][4] = {};
    for (int kb = 0; kb < 256; kb += 16) {
        float4 av = make_float4(0.f, 0.f, 0.f, 0.f);
        if (aval) av = *(const float4*)(Arow + kb + lk0);
        float4 bv0 = *(const float4*)(B + (size_t)(kb + lbk) * 128 + lbn0);
        float4 bv1 = *(const float4*)(B + (size_t)(kb + lbk) * 128 + lbn0 + 4);
        As[lk0 + 0][lm] = av.x;
        As[lk0 + 1][lm] = av.y;
        As[lk0 + 2][lm] = av.z;
        As[lk0 + 3][lm] = av.w;
        *(float4*)&Bs[lbk][lbn0]     = bv0;
        *(float4*)&Bs[lbk][lbn0 + 4] = bv1;
        __syncthreads();
        #pragma unroll
        for (int kk = 0; kk < 16; ++kk) {
            float4 a0 = *(const float4*)&As[kk][tm0];
            float4 a1 = *(const float4*)&As[kk][tm0 + 4];
            float4 b  = *(const float4*)&Bs[kk][tn0];
            float am[8] = {a0.x, a0.y, a0.z, a0.w, a1.x, a1.y, a1.z, a1.w};
            float bn[4] = {b.x, b.y, b.z, b.w};
            #pragma unroll
            for (int i = 0; i < 8; ++i)
                #pragma unroll
                for (int jx = 0; jx < 4; ++jx)
                    acc[i][jx] += am[i] * bn[jx];
        }
        __syncthreads();
    }
    #pragma unroll
    for (int i = 0; i < 8; ++i) {
        int r = bm0 + tm0 + i;
        if (r < M) {
            float w = dis[r];
            float4 o = make_float4(acc[i][0] * w, acc[i][1] * w,
                                   acc[i][2] * w, acc[i][3] * w);
            *(float4*)(C + (size_t)r * 128 + tn0) = o;
        }
    }
}

// ---------------- prop128: wave/node, half-wave/edge, float4 lanes ----------------
// input rows pre-scaled by dis[src]; epilogue applies dis[n], bias, leaky
__global__ __launch_bounds__(256) void prop128(
        const float* __restrict__ h, const int* __restrict__ rowptr,
        const int* __restrict__ col, const float* __restrict__ dis,
        const float* __restrict__ bias, float* __restrict__ out, int N) {
    int n = (blockIdx.x * 256 + threadIdx.x) >> 6;
    if (n >= N) return;
    int lane = threadIdx.x & 63;
    int half = lane >> 5;        // edge slot parity
    int q = lane & 31;           // float4 index in row (32 x 16B = 512B row)
    const float4* __restrict__ h4 = (const float4*)h;
    int beg = rowptr[n], end = rowptr[n + 1];
    float ax = 0.f, ay = 0.f, az = 0.f, aw = 0.f;
    int j = beg + half;
    for (; j + 2 < end; j += 4) {          // 4 edges in flight per wave
        int s0 = col[j];
        int s1 = col[j + 2];
        float4 v0 = h4[(size_t)s0 * 32 + q];
        float4 v1 = h4[(size_t)s1 * 32 + q];
        ax += v0.x; ay += v0.y; az += v0.z; aw += v0.w;
        ax += v1.x; ay += v1.y; az += v1.z; aw += v1.w;
    }
    for (; j < end; j += 2) {
        int s = col[j];
        float4 v = h4[(size_t)s * 32 + q];
        ax += v.x; ay += v.y; az += v.z; aw += v.w;
    }
    ax += __shfl_xor(ax, 32);
    ay += __shfl_xor(ay, 32);
    az += __shfl_xor(az, 32);
    aw += __shfl_xor(aw, 32);
    if (half == 0) {
        float dn = dis[n];
        float4 bv = ((const float4*)bias)[q];
        float ox = fmaf(dn, ax, bv.x);
        float oy = fmaf(dn, ay, bv.y);
        float oz = fmaf(dn, az, bv.z);
        float ow = fmaf(dn, aw, bv.w);
        ox = ox > 0.f ? ox : LEAKY * ox;
        oy = oy > 0.f ? oy : LEAKY * oy;
        oz = oz > 0.f ? oz : LEAKY * oz;
        ow = ow > 0.f ? ow : LEAKY * ow;
        ((float4*)out)[(size_t)n * 32 + q] = make_float4(ox, oy, oz, ow);
    }
}

// ---------------- GEMM2: [M,128] @ [128,16], epilogue *= dis[row] ----------------
__global__ __launch_bounds__(256) void gemm_128_16(
        const float* __restrict__ A, const float* __restrict__ W,
        const float* __restrict__ dis, float* __restrict__ C, int M) {
    __shared__ float sx[64 * 129];
    __shared__ float sw[128 * 16];
    int t = threadIdx.x;
    int n0 = blockIdx.x * 64;
    for (int i = t; i < 2048; i += 256) sw[i] = W[i];
    #pragma unroll
    for (int i = 0; i < 32; ++i) {
        int l = t + i * 256;
        int node = l >> 7, k = l & 127;
        int gn = n0 + node;
        sx[node * 129 + k] = (gn < M) ? A[(size_t)gn * 128 + k] : 0.f;
    }
    __syncthreads();
    int n = t >> 2;
    int c0 = (t & 3) * 4;
    const float4* sw4 = (const float4*)sw;
    float4 acc = make_float4(0.f, 0.f, 0.f, 0.f);
    for (int k = 0; k < 128; ++k) {
        float xv = sx[n * 129 + k];
        float4 wv = sw4[k * 4 + (t & 3)];
        acc.x += xv * wv.x; acc.y += xv * wv.y;
        acc.z += xv * wv.z; acc.w += xv * wv.w;
    }
    int gn = n0 + n;
    if (gn < M) {
        float w = dis[gn];
        float* dst = C + (size_t)gn * 16 + c0;
        dst[0] = acc.x * w; dst[1] = acc.y * w;
        dst[2] = acc.z * w; dst[3] = acc.w * w;
    }
}

// ---------------- prop16: 16 lanes/node, 4 edge slots x float4 ----------------
// input rows pre-scaled by dis[src]; post=1 additionally scales output by dis[n]
__global__ __launch_bounds__(256) void prop16(
        const float* __restrict__ h, const int* __restrict__ rowptr,
        const int* __restrict__ col, const float* __restrict__ dis,
        const float* __restrict__ bias, float* __restrict__ out,
        int N, int act, int post) {
    int t = blockIdx.x * 256 + threadIdx.x;
    int n = t >> 4;
    if (n >= N) return;
    int li = threadIdx.x & 15;
    int eo = li >> 2;            // edge slot 0..3
    int fq = li & 3;             // float4 index in 16-float row
    const float4* __restrict__ h4 = (const float4*)h;
    int beg = rowptr[n], end = rowptr[n + 1];
    float ax = 0.f, ay = 0.f, az = 0.f, aw = 0.f;
    for (int j = beg + eo; j < end; j += 4) {   // 4 edges in flight per node
        int s = col[j];
        float4 v = h4[(size_t)s * 4 + fq];
        ax += v.x; ay += v.y; az += v.z; aw += v.w;
    }
    ax += __shfl_xor(ax, 4); ax += __shfl_xor(ax, 8);
    ay += __shfl_xor(ay, 4); ay += __shfl_xor(ay, 8);
    az += __shfl_xor(az, 4); az += __shfl_xor(az, 8);
    aw += __shfl_xor(aw, 4); aw += __shfl_xor(aw, 8);
    if (eo == 0) {
        float dn = dis[n];
        float ox = dn * ax, oy = dn * ay, oz = dn * az, ow = dn * aw;
        if (act) {
            float4 bv = ((const float4*)bias)[fq];
            ox += bv.x; oy += bv.y; oz += bv.z; ow += bv.w;
            ox = ox > 0.f ? ox : LEAKY * ox;
            oy = oy > 0.f ? oy : LEAKY * oy;
            oz = oz > 0.f ? oz : LEAKY * oz;
            ow = ow > 0.f ? ow : LEAKY * ow;
        }
        if (post) { ox *= dn; oy *= dn; oz *= dn; ow *= dn; }
        ((float4*)out)[(size_t)n * 4 + fq] = make_float4(ox, oy, oz, ow);
    }
}

// ---------------- GEMM3: [M,16] @ [16,40] + b ----------------
__global__ __launch_bounds__(256) void gemm_16_40(
        const float* __restrict__ P, const float* __restrict__ W,
        const float* __restrict__ b, float* __restrict__ out, int total) {
    __shared__ float sw[16 * 40];
    __shared__ float sb[40];
    int t = threadIdx.x;
    for (int i = t; i < 640; i += 256) sw[i] = W[i];
    if (t < 40) sb[t] = b[t];
    __syncthreads();
    int idx = blockIdx.x * 256 + t;
    if (idx >= total) return;
    int n = idx / 40, c = idx % 40;
    float acc = sb[c];
    const float* pr = P + (size_t)n * 16;
    #pragma unroll
    for (int k = 0; k < 16; ++k) acc += pr[k] * sw[k * 40 + c];
    out[idx] = acc;
}

// ---------------- launch ----------------

extern "C" void kernel_launch(void* const* d_in, const int* in_sizes, int n_in,
                              void* d_out, int out_size, void* d_ws, size_t ws_size,
                              hipStream_t stream) {
    const float* x  = (const float*)d_in[0];
    const int*   ei = (const int*)d_in[1];
    const float* W1 = (const float*)d_in[2];
    const float* b1 = (const float*)d_in[3];
    const float* W2 = (const float*)d_in[4];
    const float* b2 = (const float*)d_in[5];
    const float* W3 = (const float*)d_in[6];
    const float* b3 = (const float*)d_in[7];
    float* out = (float*)d_out;

    int N = in_sizes[0] / 256;   // 100000
    int E = in_sizes[1] / 2;     // 3200000
    const int* src = ei;
    const int* dst = ei + E;

    char* w = (char*)d_ws;
    auto alloc = [&](size_t bytes) {
        char* p = w;
        w += (bytes + 255) & ~(size_t)255;
        return p;
    };
    int NB = (N + 255) / 256;
    int*   cnt     = (int*)  alloc((size_t)N * 4);
    int*   rowptr  = (int*)  alloc((size_t)(N + 1) * 4);
    int*   fillpos = (int*)  alloc((size_t)N * 4);
    int*   bsum    = (int*)  alloc((size_t)NB * 4);
    int*   colx    = (int*)  alloc((size_t)(E + N) * 4);
    float* dis     = (float*)alloc((size_t)N * 4);
    float* bufA    = (float*)alloc((size_t)N * 128 * 4);
    float* bufB    = (float*)alloc((size_t)N * 128 * 4);

    float* h1 = bufA;                       // [N,128] (pre-scaled by dis)
    float* x1 = bufB;                       // [N,128]
    float* h2 = bufA;                       // [N,16]  (pre-scaled by dis)
    float* x2 = bufA + (size_t)N * 16;      // [N,16]  (pre-scaled by dis)
    float* p3 = bufA + (size_t)N * 32;      // [N,16]

    int gN = (N + 255) / 256;
    init_kernel <<<gN, 256, 0, stream>>>(cnt, fillpos, N);
    count_kernel<<<(E + 255) / 256, 256, 0, stream>>>(dst, cnt, E);
    dis_kernel  <<<gN, 256, 0, stream>>>(cnt, dis, N);
    scan_block  <<<NB, 256, 0, stream>>>(cnt, rowptr, bsum, N);
    scan_tops   <<<1, 512, 0, stream>>>(bsum, NB, rowptr, N);
    scan_add    <<<NB, 256, 0, stream>>>(rowptr, bsum, N);
    fill_kernel <<<(E + N + 255) / 256, 256, 0, stream>>>(src, dst, rowptr,
                                                          fillpos, colx, E, N);

    gemm_256_128<<<(N + 63) / 64, 256, 0, stream>>>(x, W1, dis, h1, N);
    prop128     <<<(N * 64 + 255) / 256, 256, 0, stream>>>(h1, rowptr, colx,
                                                           dis, b1, x1, N);
    gemm_128_16 <<<(N + 63) / 64, 256, 0, stream>>>(x1, W2, dis, h2, N);
    prop16      <<<(N * 16 + 255) / 256, 256, 0, stream>>>(h2, rowptr, colx,
                                                           dis, b2, x2, N, 1, 1);
    prop16      <<<(N * 16 + 255) / 256, 256, 0, stream>>>(x2, rowptr, colx,
                                                           dis, nullptr, p3, N, 0, 0);
    gemm_16_40  <<<(N * 40 + 255) / 256, 256, 0, stream>>>(p3, W3, b3, out,
                                                           N * 40);
}

// Round 3
// 702.853 us; speedup vs baseline: 1.5518x; 1.2531x over previous
//
#include <hip/hip_runtime.h>
#include <hip/hip_fp16.h>
#include <math.h>

#define LEAKY 0.2f

union H2 { __half2 h; int i; };
union H4 { __half2 h[2]; float2 f; };
union H8 { __half2 h[4]; float4 f; };

__device__ inline __half2 shfl_xor_h2(__half2 v, int m) {
    H2 u; u.h = v;
    u.i = __shfl_xor(u.i, m);
    return u.h;
}

// ---------------- CSR build ----------------

__global__ void init_kernel(int* cnt, int* fillpos, int N) {
    int i = blockIdx.x * blockDim.x + threadIdx.x;
    if (i < N) { cnt[i] = 1; fillpos[i] = 0; }  // 1 = self-loop
}

__global__ void count_kernel(const int* __restrict__ dst, int* cnt, int E) {
    int e = blockIdx.x * blockDim.x + threadIdx.x;
    if (e < E) atomicAdd(&cnt[dst[e]], 1);
}

__global__ void dis_kernel(const int* __restrict__ cnt, float* dis, int N) {
    int i = blockIdx.x * blockDim.x + threadIdx.x;
    if (i < N) dis[i] = 1.0f / sqrtf((float)cnt[i]);
}

__global__ void scan_block(const int* __restrict__ cnt, int* rowptr, int* bsum, int n) {
    __shared__ int s[256];
    int t = threadIdx.x;
    int i = blockIdx.x * 256 + t;
    int v = (i < n) ? cnt[i] : 0;
    s[t] = v; __syncthreads();
    for (int off = 1; off < 256; off <<= 1) {
        int a = (t >= off) ? s[t - off] : 0;
        __syncthreads();
        s[t] += a;
        __syncthreads();
    }
    if (i < n) rowptr[i] = s[t] - v;
    if (t == 255) bsum[blockIdx.x] = s[255];
}

__global__ void scan_tops(int* bsum, int nb, int* rowptr, int n) {
    __shared__ int s[512];
    int t = threadIdx.x;
    int v = (t < nb) ? bsum[t] : 0;
    s[t] = v; __syncthreads();
    for (int off = 1; off < 512; off <<= 1) {
        int a = (t >= off) ? s[t - off] : 0;
        __syncthreads();
        s[t] += a;
        __syncthreads();
    }
    if (t < nb) bsum[t] = s[t] - v;
    if (t == 511) rowptr[n] = s[511];
}

__global__ void scan_add(int* rowptr, const int* __restrict__ bsum, int n) {
    int i = blockIdx.x * 256 + threadIdx.x;
    if (i < n) rowptr[i] += bsum[blockIdx.x];
}

__global__ void fill_kernel(const int* __restrict__ src, const int* __restrict__ dst,
                            const int* __restrict__ rowptr, int* fillpos, int* col,
                            int E, int N) {
    int e = blockIdx.x * blockDim.x + threadIdx.x;
    if (e >= E + N) return;
    int s, d;
    if (e < E) { s = src[e]; d = dst[e]; }
    else       { s = e - E;  d = s; }      // self-loop
    int pos = atomicAdd(&fillpos[d], 1);
    col[rowptr[d] + pos] = s;
}

// ---------------- GEMM1: [M,256] @ [256,128] -> fp16, epilogue *= dis[row] ----------------
// 64x128 tile, 256 threads, 8x4 micro-tile, BK=16, packed-fp16 FMA
__global__ __launch_bounds__(256) void gemm_256_128(
        const float* __restrict__ A, const float* __restrict__ B,
        const float* __restrict__ dis, __half* __restrict__ C, int M) {
    __shared__ __align__(16) __half As[16][72];
    __shared__ __align__(16) __half Bs[16][136];
    int t = threadIdx.x;
    int bm0 = blockIdx.x * 64;
    int lm  = t >> 2;            // A-load row 0..63
    int lk0 = (t & 3) * 4;       // A-load k base
    int lbk  = t >> 4;           // B-load k 0..15
    int lbn0 = (t & 15) * 8;     // B-load n base
    int arow = bm0 + lm;
    bool aval = arow < M;
    const float* Arow = A + (size_t)arow * 256;
    int tm0 = (t >> 5) * 8;      // micro row base
    int tn0 = (t & 31) * 4;      // micro col base
    __half2 acc[8][2];
    #pragma unroll
    for (int i = 0; i < 8; ++i) {
        acc[i][0] = __float2half2_rn(0.f);
        acc[i][1] = __float2half2_rn(0.f);
    }
    for (int kb = 0; kb < 256; kb += 16) {
        float4 av = make_float4(0.f, 0.f, 0.f, 0.f);
        if (aval) av = *(const float4*)(Arow + kb + lk0);
        float4 bv0 = *(const float4*)(B + (size_t)(kb + lbk) * 128 + lbn0);
        float4 bv1 = *(const float4*)(B + (size_t)(kb + lbk) * 128 + lbn0 + 4);
        As[lk0 + 0][lm] = __float2half(av.x);
        As[lk0 + 1][lm] = __float2half(av.y);
        As[lk0 + 2][lm] = __float2half(av.z);
        As[lk0 + 3][lm] = __float2half(av.w);
        H8 bu;
        bu.h[0] = __floats2half2_rn(bv0.x, bv0.y);
        bu.h[1] = __floats2half2_rn(bv0.z, bv0.w);
        bu.h[2] = __floats2half2_rn(bv1.x, bv1.y);
        bu.h[3] = __floats2half2_rn(bv1.z, bv1.w);
        *(float4*)&Bs[lbk][lbn0] = bu.f;
        __syncthreads();
        #pragma unroll
        for (int kk = 0; kk < 16; ++kk) {
            const __half2* ap = (const __half2*)&As[kk][tm0];
            __half2 a01 = ap[0], a23 = ap[1], a45 = ap[2], a67 = ap[3];
            const __half2* bp = (const __half2*)&Bs[kk][tn0];
            __half2 b01 = bp[0], b23 = bp[1];
            acc[0][0] = __hfma2(__low2half2(a01),  b01, acc[0][0]);
            acc[0][1] = __hfma2(__low2half2(a01),  b23, acc[0][1]);
            acc[1][0] = __hfma2(__high2half2(a01), b01, acc[1][0]);
            acc[1][1] = __hfma2(__high2half2(a01), b23, acc[1][1]);
            acc[2][0] = __hfma2(__low2half2(a23),  b01, acc[2][0]);
            acc[2][1] = __hfma2(__low2half2(a23),  b23, acc[2][1]);
            acc[3][0] = __hfma2(__high2half2(a23), b01, acc[3][0]);
            acc[3][1] = __hfma2(__high2half2(a23), b23, acc[3][1]);
            acc[4][0] = __hfma2(__low2half2(a45),  b01, acc[4][0]);
            acc[4][1] = __hfma2(__low2half2(a45),  b23, acc[4][1]);
            acc[5][0] = __hfma2(__high2half2(a45), b01, acc[5][0]);
            acc[5][1] = __hfma2(__high2half2(a45), b23, acc[5][1]);
            acc[6][0] = __hfma2(__low2half2(a67),  b01, acc[6][0]);
            acc[6][1] = __hfma2(__low2half2(a67),  b23, acc[6][1]);
            acc[7][0] = __hfma2(__high2half2(a67), b01, acc[7][0]);
            acc[7][1] = __hfma2(__high2half2(a67), b23, acc[7][1]);
        }
        __syncthreads();
    }
    #pragma unroll
    for (int i = 0; i < 8; ++i) {
        int r = bm0 + tm0 + i;
        if (r < M) {
            __half2 dh = __float2half2_rn(dis[r]);
            H4 o;
            o.h[0] = __hmul2(acc[i][0], dh);
            o.h[1] = __hmul2(acc[i][1], dh);
            *(float2*)(C + (size_t)r * 128 + tn0) = o.f;
        }
    }
}

// ---------------- prop128: wave/node, 4 edge slots x 16 lanes x float4(8 halves) ----------------
// input rows fp16 pre-scaled by dis[src]; epilogue applies dis[n], bias, leaky; fp16 out
__global__ __launch_bounds__(256) void prop128(
        const __half* __restrict__ h, const int* __restrict__ rowptr,
        const int* __restrict__ col, const float* __restrict__ dis,
        const float* __restrict__ bias, __half* __restrict__ out, int N) {
    int n = (blockIdx.x * 256 + threadIdx.x) >> 6;
    if (n >= N) return;
    int lane = threadIdx.x & 63;
    int eo = lane >> 4;          // edge slot 0..3
    int q = lane & 15;           // float4 index in 256B row
    const float4* __restrict__ h4 = (const float4*)h;
    int beg = rowptr[n], end = rowptr[n + 1];
    __half2 acc[4];
    acc[0] = acc[1] = acc[2] = acc[3] = __float2half2_rn(0.f);
    int j = beg + eo;
    for (; j + 4 < end; j += 8) {      // 8 edges in flight per wave
        int s0 = col[j];
        int s1 = col[j + 4];
        H8 u0, u1;
        u0.f = h4[(size_t)s0 * 16 + q];
        u1.f = h4[(size_t)s1 * 16 + q];
        acc[0] = __hadd2(acc[0], u0.h[0]);
        acc[1] = __hadd2(acc[1], u0.h[1]);
        acc[2] = __hadd2(acc[2], u0.h[2]);
        acc[3] = __hadd2(acc[3], u0.h[3]);
        acc[0] = __hadd2(acc[0], u1.h[0]);
        acc[1] = __hadd2(acc[1], u1.h[1]);
        acc[2] = __hadd2(acc[2], u1.h[2]);
        acc[3] = __hadd2(acc[3], u1.h[3]);
    }
    for (; j < end; j += 4) {
        int s = col[j];
        H8 u; u.f = h4[(size_t)s * 16 + q];
        acc[0] = __hadd2(acc[0], u.h[0]);
        acc[1] = __hadd2(acc[1], u.h[1]);
        acc[2] = __hadd2(acc[2], u.h[2]);
        acc[3] = __hadd2(acc[3], u.h[3]);
    }
    #pragma unroll
    for (int i = 0; i < 4; ++i) {
        acc[i] = __hadd2(acc[i], shfl_xor_h2(acc[i], 16));
        acc[i] = __hadd2(acc[i], shfl_xor_h2(acc[i], 32));
    }
    if (eo == 0) {
        float dn = dis[n];
        const float4* b4 = (const float4*)bias;
        float4 bA = b4[q * 2];
        float4 bB = b4[q * 2 + 1];
        float2 f0 = __half22float2(acc[0]);
        float2 f1 = __half22float2(acc[1]);
        float2 f2 = __half22float2(acc[2]);
        float2 f3 = __half22float2(acc[3]);
        float o0 = fmaf(dn, f0.x, bA.x), o1 = fmaf(dn, f0.y, bA.y);
        float o2 = fmaf(dn, f1.x, bA.z), o3 = fmaf(dn, f1.y, bA.w);
        float o4 = fmaf(dn, f2.x, bB.x), o5 = fmaf(dn, f2.y, bB.y);
        float o6 = fmaf(dn, f3.x, bB.z), o7 = fmaf(dn, f3.y, bB.w);
        o0 = o0 > 0.f ? o0 : LEAKY * o0;  o1 = o1 > 0.f ? o1 : LEAKY * o1;
        o2 = o2 > 0.f ? o2 : LEAKY * o2;  o3 = o3 > 0.f ? o3 : LEAKY * o3;
        o4 = o4 > 0.f ? o4 : LEAKY * o4;  o5 = o5 > 0.f ? o5 : LEAKY * o5;
        o6 = o6 > 0.f ? o6 : LEAKY * o6;  o7 = o7 > 0.f ? o7 : LEAKY * o7;
        H8 w;
        w.h[0] = __floats2half2_rn(o0, o1);
        w.h[1] = __floats2half2_rn(o2, o3);
        w.h[2] = __floats2half2_rn(o4, o5);
        w.h[3] = __floats2half2_rn(o6, o7);
        ((float4*)out)[(size_t)n * 16 + q] = w.f;
    }
}

// ---------------- GEMM2: fp16[M,128] @ fp32[128,16] -> fp16, epilogue *= dis[row] ----------------
__global__ __launch_bounds__(256) void gemm_128_16(
        const __half* __restrict__ A, const float* __restrict__ W,
        const float* __restrict__ dis, __half* __restrict__ C, int M) {
    __shared__ __align__(16) __half sxh[64 * 136];
    __shared__ float sw[128 * 16];
    int t = threadIdx.x;
    int n0 = blockIdx.x * 64;
    for (int i = t; i < 2048; i += 256) sw[i] = W[i];
    #pragma unroll
    for (int i = 0; i < 4; ++i) {
        int l = t + i * 256;            // 1024 chunks of 8 halves
        int node = l >> 4, q = l & 15;
        int gn = n0 + node;
        float4 v = make_float4(0.f, 0.f, 0.f, 0.f);
        if (gn < M) v = ((const float4*)A)[(size_t)gn * 16 + q];
        *(float4*)&sxh[node * 136 + q * 8] = v;
    }
    __syncthreads();
    int n = t >> 2;
    int c0 = (t & 3) * 4;
    const float4* sw4 = (const float4*)sw;
    float4 acc = make_float4(0.f, 0.f, 0.f, 0.f);
    for (int k = 0; k < 128; k += 2) {
        __half2 xv2 = *(const __half2*)&sxh[n * 136 + k];
        float2 xf = __half22float2(xv2);
        float4 w0 = sw4[k * 4 + (t & 3)];
        float4 w1 = sw4[(k + 1) * 4 + (t & 3)];
        acc.x += xf.x * w0.x + xf.y * w1.x;
        acc.y += xf.x * w0.y + xf.y * w1.y;
        acc.z += xf.x * w0.z + xf.y * w1.z;
        acc.w += xf.x * w0.w + xf.y * w1.w;
    }
    int gn = n0 + n;
    if (gn < M) {
        float w = dis[gn];
        H4 o;
        o.h[0] = __floats2half2_rn(acc.x * w, acc.y * w);
        o.h[1] = __floats2half2_rn(acc.z * w, acc.w * w);
        *(float2*)(C + (size_t)gn * 16 + c0) = o.f;
    }
}

// ---------------- prop16: 16 lanes/node, 2 edge slots x 8 lanes x int(half2), unroll 4 ----------------
// input rows fp16 pre-scaled by dis[src]
__global__ __launch_bounds__(256) void prop16(
        const __half* __restrict__ h, const int* __restrict__ rowptr,
        const int* __restrict__ col, const float* __restrict__ dis,
        const float* __restrict__ bias, void* __restrict__ outp,
        int N, int act, int post, int out_fp16) {
    int t = blockIdx.x * 256 + threadIdx.x;
    int n = t >> 4;
    if (n >= N) return;
    int li = threadIdx.x & 15;
    int eo = li >> 3;            // edge slot 0..1
    int hq = li & 7;             // half2 index in 32B row
    const int* __restrict__ h2i = (const int*)h;
    int beg = rowptr[n], end = rowptr[n + 1];
    __half2 acc = __float2half2_rn(0.f);
    int j = beg + eo;
    for (; j + 6 < end; j += 8) {      // 8 edges in flight per node
        H2 u0, u1, u2, u3;
        u0.i = h2i[(size_t)col[j]     * 8 + hq];
        u1.i = h2i[(size_t)col[j + 2] * 8 + hq];
        u2.i = h2i[(size_t)col[j + 4] * 8 + hq];
        u3.i = h2i[(size_t)col[j + 6] * 8 + hq];
        acc = __hadd2(acc, u0.h);
        acc = __hadd2(acc, u1.h);
        acc = __hadd2(acc, u2.h);
        acc = __hadd2(acc, u3.h);
    }
    for (; j < end; j += 2) {
        H2 u; u.i = h2i[(size_t)col[j] * 8 + hq];
        acc = __hadd2(acc, u.h);
    }
    acc = __hadd2(acc, shfl_xor_h2(acc, 8));
    if (eo == 0) {
        float dn = dis[n];
        float2 f = __half22float2(acc);
        float ox = dn * f.x, oy = dn * f.y;
        if (act) {
            ox += bias[hq * 2];
            oy += bias[hq * 2 + 1];
            ox = ox > 0.f ? ox : LEAKY * ox;
            oy = oy > 0.f ? oy : LEAKY * oy;
        }
        if (post) { ox *= dn; oy *= dn; }
        if (out_fp16) {
            H2 w; w.h = __floats2half2_rn(ox, oy);
            ((int*)outp)[(size_t)n * 8 + hq] = w.i;
        } else {
            ((float2*)outp)[(size_t)n * 8 + hq] = make_float2(ox, oy);
        }
    }
}

// ---------------- GEMM3: [M,16] @ [16,40] + b ----------------
__global__ __launch_bounds__(256) void gemm_16_40(
        const float* __restrict__ P, const float* __restrict__ W,
        const float* __restrict__ b, float* __restrict__ out, int total) {
    __shared__ float sw[16 * 40];
    __shared__ float sb[40];
    int t = threadIdx.x;
    for (int i = t; i < 640; i += 256) sw[i] = W[i];
    if (t < 40) sb[t] = b[t];
    __syncthreads();
    int idx = blockIdx.x * 256 + t;
    if (idx >= total) return;
    int n = idx / 40, c = idx % 40;
    float acc = sb[c];
    const float* pr = P + (size_t)n * 16;
    #pragma unroll
    for (int k = 0; k < 16; ++k) acc += pr[k] * sw[k * 40 + c];
    out[idx] = acc;
}

// ---------------- launch ----------------

extern "C" void kernel_launch(void* const* d_in, const int* in_sizes, int n_in,
                              void* d_out, int out_size, void* d_ws, size_t ws_size,
                              hipStream_t stream) {
    const float* x  = (const float*)d_in[0];
    const int*   ei = (const int*)d_in[1];
    const float* W1 = (const float*)d_in[2];
    const float* b1 = (const float*)d_in[3];
    const float* W2 = (const float*)d_in[4];
    const float* b2 = (const float*)d_in[5];
    const float* W3 = (const float*)d_in[6];
    const float* b3 = (const float*)d_in[7];
    float* out = (float*)d_out;

    int N = in_sizes[0] / 256;   // 100000
    int E = in_sizes[1] / 2;     // 3200000
    const int* src = ei;
    const int* dst = ei + E;

    char* w = (char*)d_ws;
    auto alloc = [&](size_t bytes) {
        char* p = w;
        w += (bytes + 255) & ~(size_t)255;
        return p;
    };
    int NB = (N + 255) / 256;
    int*    cnt     = (int*)   alloc((size_t)N * 4);
    int*    rowptr  = (int*)   alloc((size_t)(N + 1) * 4);
    int*    fillpos = (int*)   alloc((size_t)N * 4);
    int*    bsum    = (int*)   alloc((size_t)NB * 4);
    int*    colx    = (int*)   alloc((size_t)(E + N) * 4);
    float*  dis     = (float*) alloc((size_t)N * 4);
    __half* h1h     = (__half*)alloc((size_t)N * 128 * 2);
    __half* x1h     = (__half*)alloc((size_t)N * 128 * 2);
    __half* h2h     = (__half*)alloc((size_t)N * 16 * 2);
    __half* x2h     = (__half*)alloc((size_t)N * 16 * 2);
    float*  p3      = (float*) alloc((size_t)N * 16 * 4);

    int gN = (N + 255) / 256;
    init_kernel <<<gN, 256, 0, stream>>>(cnt, fillpos, N);
    count_kernel<<<(E + 255) / 256, 256, 0, stream>>>(dst, cnt, E);
    dis_kernel  <<<gN, 256, 0, stream>>>(cnt, dis, N);
    scan_block  <<<NB, 256, 0, stream>>>(cnt, rowptr, bsum, N);
    scan_tops   <<<1, 512, 0, stream>>>(bsum, NB, rowptr, N);
    scan_add    <<<NB, 256, 0, stream>>>(rowptr, bsum, N);
    fill_kernel <<<(E + N + 255) / 256, 256, 0, stream>>>(src, dst, rowptr,
                                                          fillpos, colx, E, N);

    gemm_256_128<<<(N + 63) / 64, 256, 0, stream>>>(x, W1, dis, h1h, N);
    prop128     <<<(N * 64 + 255) / 256, 256, 0, stream>>>(h1h, rowptr, colx,
                                                           dis, b1, x1h, N);
    gemm_128_16 <<<(N + 63) / 64, 256, 0, stream>>>(x1h, W2, dis, h2h, N);
    prop16      <<<(N * 16 + 255) / 256, 256, 0, stream>>>(h2h, rowptr, colx,
                                                           dis, b2, x2h, N, 1, 1, 1);
    prop16      <<<(N * 16 + 255) / 256, 256, 0, stream>>>(x2h, rowptr, colx,
                                                           dis, nullptr, p3, N, 0, 0, 0);
    gemm_16_40  <<<(N * 40 + 255) / 256, 256, 0, stream>>>(p3, W3, b3, out,
                                                           N * 40);
}